// Round 3
// baseline (232.871 us; speedup 1.0000x reference)
//
#include <hip/hip_runtime.h>
#include <hip/hip_bf16.h>

#define NOBJ 21

typedef __bf16 bf16x8 __attribute__((ext_vector_type(8)));
typedef float f32x16 __attribute__((ext_vector_type(16)));
typedef float f32x4  __attribute__((ext_vector_type(4)));

__device__ __forceinline__ float ftanh(float x) {
    // tanh(x) = 1 - 2/(exp(2x)+1); saturates exactly via rcp(inf)=0.
    float e = __expf(2.0f * x);
    float r = __builtin_amdgcn_rcpf(e + 1.0f);
    return __builtin_fmaf(-2.0f, r, 1.0f);
}

// fe3[c][e] = tanh(tanh(emb[c]) @ We + be); w2t = frag-major bf16 Wm2 table:
// fi = (ct*8+ks)*64+lane -> elem e is Wm2[ks*16+(lane>>5)*8+e][ct*32+(lane&31)]
__global__ void setup_kernel(const float* __restrict__ emb, const float* __restrict__ We,
                             const float* __restrict__ be, const float* __restrict__ Wm2,
                             float* __restrict__ fe3, __bf16* __restrict__ w2t, int do_w2t) {
    int t = threadIdx.x;
    if (t < 192) {
        int cc = t >> 6, e = t & 63;
        float acc = be[e];
        for (int k = 0; k < 64; ++k)
            acc += ftanh(emb[cc * 64 + k]) * We[k * 64 + e];
        fe3[t] = ftanh(acc);
    }
    if (do_w2t) {
        for (int fi = t; fi < 2048; fi += 256) {
            int ct = fi >> 9, ks = (fi >> 6) & 7, ln = fi & 63;
            int n  = ct * 32 + (ln & 31);
            int k0 = ks * 16 + (ln >> 5) * 8;
            bf16x8 v;
            #pragma unroll
            for (int e = 0; e < 8; ++e) v[e] = (__bf16)Wm2[(k0 + e) * 128 + n];
            *reinterpret_cast<bf16x8*>(&w2t[fi * 8]) = v;
        }
    }
}

// u/v fp32 LDS with 16B-chunk XOR swizzle (row-major [21][128], chunk=k>>2)
__device__ __forceinline__ int uvswz(int row, int k) {
    return row * 128 + (((k >> 2) ^ (row & 15)) << 2) + (k & 3);
}

// LDS layout (bytes), total 40320 -> 4 blocks/CU:
//   uL  f32 swz [21][128] @ 0      (10752)
//   vL  f32 swz [21][128] @ 10752  (10752)
//   xL  bf16    [21][128] @ 21504  (5376)   [spl/cat overlay here pre-phase2]
//   hL  bf16    [21][128] @ 26880  (5376) \ overlay: a1L f32 [21][128] @26880
//   fL  bf16    [21][192] @ 32256  (8064) /
#define SMEM_SZ 40320

template<int USE_WS>
__global__ __launch_bounds__(256, 4)
void actor_kernel(const float* __restrict__ state, const float* __restrict__ ts,
                  const float* __restrict__ Ws1, const float* __restrict__ bs1,
                  const float* __restrict__ Ws2, const float* __restrict__ bs2,
                  const float* __restrict__ Wm1, const float* __restrict__ bm1,
                  const float* __restrict__ Wm2, const float* __restrict__ bm2,
                  const float* __restrict__ Wa1, const float* __restrict__ ba1,
                  const float* __restrict__ Wa2, const float* __restrict__ ba2,
                  const float* __restrict__ fe3, const __bf16* __restrict__ w2t,
                  float* __restrict__ out) {
    __shared__ __align__(16) unsigned char smem[SMEM_SZ];
    float*  uL  = (float*)(smem);
    float*  vL  = (float*)(smem + 10752);
    __bf16* xL  = (__bf16*)(smem + 21504);
    float*  spl = (float*)(smem + 21504);
    int*    catl= (int*)(smem + 21840);
    __bf16* hL  = (__bf16*)(smem + 26880);
    __bf16* fL  = (__bf16*)(smem + 32256);
    float*  a1L = (float*)(smem + 26880);

    const int b   = blockIdx.x;
    const int tid = threadIdx.x;
    const int c   = tid & 127;
    const int half= tid >> 7;
    const int i0  = half ? 11 : 0;
    const int NI  = half ? (NOBJ - 11) : 11;

    // ---- step 0: per-object scalars ----
    if (tid < NOBJ * 4) {
        int i = tid >> 2, m = tid & 3;
        float v;
        if (m < 2) v = state[b * 63 + i * 3 + m];
        else       v = ftanh(ts[(b * NOBJ + i) * 2 + (m - 2)]);
        spl[tid] = v;
    }
    if (tid >= 128 && tid < 128 + NOBJ) {
        int i = tid - 128;
        catl[i] = (int)state[b * 63 + i * 3 + 2];
    }
    __syncthreads();

    // ---- step 1: h = tanh(sp @ Ws1 + bs1) -> bf16 ----
    {
        float b1 = bs1[c];
        float w0 = Ws1[0 * 128 + c], w1 = Ws1[1 * 128 + c];
        float w2 = Ws1[2 * 128 + c], w3 = Ws1[3 * 128 + c];
        for (int g = 0; g < NI; ++g) {
            int i = i0 + g;
            float acc = b1 + spl[i*4+0]*w0 + spl[i*4+1]*w1 + spl[i*4+2]*w2 + spl[i*4+3]*w3;
            hL[i * 128 + c] = (__bf16)ftanh(acc);
        }
    }
    __syncthreads();

    // ---- step 2: f[:, :128] = tanh(h @ Ws2 + bs2) (bf16-pair reads) ----
    {
        float acc[11];
        #pragma unroll
        for (int g = 0; g < 11; ++g) acc[g] = 0.f;
        const unsigned int* hrow = (const unsigned int*)hL;  // row stride 64 dwords
        for (int k2 = 0; k2 < 64; ++k2) {
            float w0 = Ws2[(2 * k2) * 128 + c];
            float w1 = Ws2[(2 * k2 + 1) * 128 + c];
            #pragma unroll
            for (int g = 0; g < 11; ++g) {
                if (g < NI) {
                    unsigned int pr = hrow[(i0 + g) * 64 + k2];
                    float lo = __uint_as_float(pr << 16);
                    float hi = __uint_as_float(pr & 0xffff0000u);
                    acc[g] = __builtin_fmaf(hi, w1, __builtin_fmaf(lo, w0, acc[g]));
                }
            }
        }
        float b2 = bs2[c];
        for (int g = 0; g < NI; ++g)
            fL[(i0 + g) * 192 + c] = (__bf16)ftanh(acc[g] + b2);
    }
    for (int idx = tid; idx < NOBJ * 64; idx += 256) {
        int i = idx >> 6, e = idx & 63;
        fL[i * 192 + 128 + e] = (__bf16)fe3[catl[i] * 64 + e];
    }
    __syncthreads();

    // ---- step 3: u = f@(Wm1_top - Wm1_bot) + bm1 ; v = f@Wm1_bot (swizzled f32) ----
    {
        float ua[11], va[11];
        #pragma unroll
        for (int g = 0; g < 11; ++g) { ua[g] = 0.f; va[g] = 0.f; }
        const unsigned int* frow = (const unsigned int*)fL;  // row stride 96 dwords
        for (int k2 = 0; k2 < 96; ++k2) {
            int k = 2 * k2;
            float wt0 = Wm1[k * 128 + c],         wt1 = Wm1[(k + 1) * 128 + c];
            float wb0 = Wm1[(192 + k) * 128 + c], wb1 = Wm1[(193 + k) * 128 + c];
            float wd0 = wt0 - wb0, wd1 = wt1 - wb1;
            #pragma unroll
            for (int g = 0; g < 11; ++g) {
                if (g < NI) {
                    unsigned int pr = frow[(i0 + g) * 96 + k2];
                    float lo = __uint_as_float(pr << 16);
                    float hi = __uint_as_float(pr & 0xffff0000u);
                    ua[g] = __builtin_fmaf(hi, wd1, __builtin_fmaf(lo, wd0, ua[g]));
                    va[g] = __builtin_fmaf(hi, wb1, __builtin_fmaf(lo, wb0, va[g]));
                }
            }
        }
        float b1 = bm1[c];
        for (int g = 0; g < NI; ++g) {
            uL[uvswz(i0 + g, c)] = ua[g] + b1;
            vL[uvswz(i0 + g, c)] = va[g];
        }
    }
    __syncthreads();

    // ---- phase 2: wave owns i-pairs; x[i,:] = tanh(max_j tanh(u_i+v_j)@Wm2 + bm2) ----
    const int lane = tid & 63;
    const int wave = tid >> 6;
    const int rowA = lane & 31;
    const int hi   = lane >> 5;
    float bm2v[4];
    #pragma unroll
    for (int ct = 0; ct < 4; ++ct) bm2v[ct] = bm2[ct * 32 + rowA];

    for (int p = wave; p < 11; p += 4) {
        int ia = 2 * p, ib = 2 * p + 1;   // ib may be 21 (masked)
        bf16x8 fa[8], fb[8];
        #pragma unroll
        for (int ks = 0; ks < 8; ++ks) {
            int ch0 = ks * 4 + hi * 2;
            f32x4 v0  = *(const f32x4*)&vL[rowA * 128 + (((ch0)     ^ (rowA & 15)) << 2)];
            f32x4 v1  = *(const f32x4*)&vL[rowA * 128 + (((ch0 + 1) ^ (rowA & 15)) << 2)];
            f32x4 ua0 = *(const f32x4*)&uL[ia * 128 + (((ch0)     ^ (ia & 15)) << 2)];
            f32x4 ua1 = *(const f32x4*)&uL[ia * 128 + (((ch0 + 1) ^ (ia & 15)) << 2)];
            f32x4 ub0 = *(const f32x4*)&uL[ib * 128 + (((ch0)     ^ (ib & 15)) << 2)];
            f32x4 ub1 = *(const f32x4*)&uL[ib * 128 + (((ch0 + 1) ^ (ib & 15)) << 2)];
            bf16x8 a, bb;
            #pragma unroll
            for (int e = 0; e < 4; ++e) {
                a[e]      = (__bf16)ftanh(ua0[e] + v0[e]);
                a[4 + e]  = (__bf16)ftanh(ua1[e] + v1[e]);
                bb[e]     = (__bf16)ftanh(ub0[e] + v0[e]);
                bb[4 + e] = (__bf16)ftanh(ub1[e] + v1[e]);
            }
            fa[ks] = a; fb[ks] = bb;
        }
        #pragma unroll
        for (int ct = 0; ct < 4; ++ct) {
            int cN = ct * 32 + rowA;
            f32x16 aa, ab;
            #pragma unroll
            for (int r = 0; r < 16; ++r) { aa[r] = 0.f; ab[r] = 0.f; }
            #pragma unroll
            for (int ks = 0; ks < 8; ++ks) {
                bf16x8 bb;
                if (USE_WS) {
                    int fi = (ct * 8 + ks) * 64 + lane;
                    bb = *(const bf16x8*)&w2t[fi * 8];
                } else {
                    int k0 = ks * 16 + hi * 8;
                    #pragma unroll
                    for (int e = 0; e < 8; ++e) bb[e] = (__bf16)Wm2[(k0 + e) * 128 + cN];
                }
                aa = __builtin_amdgcn_mfma_f32_32x32x16_bf16(fa[ks], bb, aa, 0, 0, 0);
                ab = __builtin_amdgcn_mfma_f32_32x32x16_bf16(fb[ks], bb, ab, 0, 0, 0);
            }
            float ma = -INFINITY, mb = -INFINITY;
            #pragma unroll
            for (int r = 0; r < 16; ++r) {
                int rowj = (r & 3) + 8 * (r >> 2) + 4 * hi;
                if (rowj < NOBJ) {
                    if (rowj != ia) ma = fmaxf(ma, aa[r]);
                    if (rowj != ib) mb = fmaxf(mb, ab[r]);
                }
            }
            ma = fmaxf(ma, __shfl_xor(ma, 32));
            mb = fmaxf(mb, __shfl_xor(mb, 32));
            if (hi == 0) {
                xL[ia * 128 + cN] = (__bf16)ftanh(ma + bm2v[ct]);
                if (ib < NOBJ) xL[ib * 128 + cN] = (__bf16)ftanh(mb + bm2v[ct]);
            }
        }
    }
    __syncthreads();

    // ---- phase 3: a1 = tanh(x @ Wa1 + ba1) (bf16-pair reads, a1 overlays h/f) ----
    {
        float acc[11];
        #pragma unroll
        for (int g = 0; g < 11; ++g) acc[g] = 0.f;
        const unsigned int* xrow = (const unsigned int*)xL;  // row stride 64 dwords
        for (int k2 = 0; k2 < 64; ++k2) {
            float w0 = Wa1[(2 * k2) * 128 + c];
            float w1 = Wa1[(2 * k2 + 1) * 128 + c];
            #pragma unroll
            for (int g = 0; g < 11; ++g) {
                if (g < NI) {
                    unsigned int pr = xrow[(i0 + g) * 64 + k2];
                    float lo = __uint_as_float(pr << 16);
                    float hi = __uint_as_float(pr & 0xffff0000u);
                    acc[g] = __builtin_fmaf(hi, w1, __builtin_fmaf(lo, w0, acc[g]));
                }
            }
        }
        float b1 = ba1[c];
        for (int g = 0; g < NI; ++g)
            a1L[(i0 + g) * 128 + c] = ftanh(acc[g] + b1);
    }
    __syncthreads();

    // ---- head: act = a1 @ Wa2 + ba2 (k rotated by i*5 to spread banks) ----
    if (tid < NOBJ * 4) {
        int i = tid >> 2, o = tid & 3;
        float acc = ba2[o];
        for (int kk = 0; kk < 128; ++kk) {
            int k = (kk + i * 5) & 127;
            acc += a1L[i * 128 + k] * Wa2[k * 4 + o];
        }
        if (o < 2) {
            out[b * 42 + i * 2 + o] = 0.3f * ftanh(acc);
        } else {
            float t   = ftanh(acc);
            float lsv = -5.0f + 3.5f * (t + 1.0f);
            out[43008 + b * 42 + i * 2 + (o - 2)] = __expf(lsv);
        }
    }
}

extern "C" void kernel_launch(void* const* d_in, const int* in_sizes, int n_in,
                              void* d_out, int out_size, void* d_ws, size_t ws_size,
                              hipStream_t stream) {
    (void)in_sizes; (void)n_in; (void)out_size;
    const float* state = (const float*)d_in[0];
    const float* ts    = (const float*)d_in[1];
    const float* emb   = (const float*)d_in[2];
    const float* We    = (const float*)d_in[3];
    const float* be    = (const float*)d_in[4];
    const float* Ws1   = (const float*)d_in[5];
    const float* bs1   = (const float*)d_in[6];
    const float* Ws2   = (const float*)d_in[7];
    const float* bs2   = (const float*)d_in[8];
    const float* Wm1   = (const float*)d_in[9];
    const float* bm1   = (const float*)d_in[10];
    const float* Wm2   = (const float*)d_in[11];
    const float* bm2   = (const float*)d_in[12];
    const float* Wa1   = (const float*)d_in[13];
    const float* ba1   = (const float*)d_in[14];
    const float* Wa2   = (const float*)d_in[15];
    const float* ba2   = (const float*)d_in[16];
    float* outp = (float*)d_out;

    float*  fe3 = (float*)d_ws;
    __bf16* w2t = (__bf16*)((char*)d_ws + 768);
    const int use_ws = (ws_size >= (size_t)(768 + 32768)) ? 1 : 0;

    setup_kernel<<<dim3(1), dim3(256), 0, stream>>>(emb, We, be, Wm2, fe3, w2t, use_ws);
    if (use_ws)
        actor_kernel<1><<<dim3(1024), dim3(256), 0, stream>>>(
            state, ts, Ws1, bs1, Ws2, bs2, Wm1, bm1, Wm2, bm2,
            Wa1, ba1, Wa2, ba2, fe3, w2t, outp);
    else
        actor_kernel<0><<<dim3(1024), dim3(256), 0, stream>>>(
            state, ts, Ws1, bs1, Ws2, bs2, Wm1, bm1, Wm2, bm2,
            Wa1, ba1, Wa2, ba2, fe3, w2t, outp);
}

// Round 4
// 149.698 us; speedup vs baseline: 1.5556x; 1.5556x over previous
//
#include <hip/hip_runtime.h>
#include <hip/hip_bf16.h>

#define NOBJ 21

typedef __bf16 bf16x8 __attribute__((ext_vector_type(8)));
typedef float f32x16 __attribute__((ext_vector_type(16)));
typedef float f32x4  __attribute__((ext_vector_type(4)));

__device__ __forceinline__ float ftanh(float x) {
    float e = __expf(2.0f * x);
    float r = __builtin_amdgcn_rcpf(e + 1.0f);
    return __builtin_fmaf(-2.0f, r, 1.0f);
}

// ---------------- setup: fe3 + frag-major bf16 weight tables ----------------
// 32x32x16 B-frag layout (verified in-kernel): col n = ct*32+(lane&31),
// k = ks*16 + (lane>>5)*8 + e.
// w2t: Wm2 (K=128 -> ks 0..8), 2048 frags, 32KB
// wdt: Wm1_top - Wm1_bot (K=192 -> ks 0..12), 3072 frags, 48KB
// wbt: Wm1_bot, 3072 frags, 48KB
__global__ void setup_kernel(const float* __restrict__ emb, const float* __restrict__ We,
                             const float* __restrict__ be, const float* __restrict__ Wm2,
                             const float* __restrict__ Wm1,
                             float* __restrict__ fe3, __bf16* __restrict__ w2t,
                             __bf16* __restrict__ wdt, __bf16* __restrict__ wbt,
                             int do_ws) {
    int t = threadIdx.x;
    if (blockIdx.x == 32) {
        if (t < 192) {
            int cc = t >> 6, e = t & 63;
            float acc = be[e];
            for (int k = 0; k < 64; ++k)
                acc += ftanh(emb[cc * 64 + k]) * We[k * 64 + e];
            fe3[t] = ftanh(acc);
        }
        return;
    }
    if (!do_ws) return;
    int fid = blockIdx.x * 256 + t;   // 0..8191
    if (fid < 2048) {
        int ct = fid >> 9, ks = (fid >> 6) & 7, ln = fid & 63;
        int n  = ct * 32 + (ln & 31);
        int k0 = ks * 16 + (ln >> 5) * 8;
        bf16x8 v;
        #pragma unroll
        for (int e = 0; e < 8; ++e) v[e] = (__bf16)Wm2[(k0 + e) * 128 + n];
        *reinterpret_cast<bf16x8*>(&w2t[fid * 8]) = v;
    } else if (fid < 5120) {
        int q = fid - 2048;
        int ct = q / 768, r = q % 768, ks = r >> 6, ln = r & 63;
        int n  = ct * 32 + (ln & 31);
        int k0 = ks * 16 + (ln >> 5) * 8;
        bf16x8 v;
        #pragma unroll
        for (int e = 0; e < 8; ++e)
            v[e] = (__bf16)(Wm1[(k0 + e) * 128 + n] - Wm1[(192 + k0 + e) * 128 + n]);
        *reinterpret_cast<bf16x8*>(&wdt[q * 8]) = v;
    } else {
        int q = fid - 5120;
        int ct = q / 768, r = q % 768, ks = r >> 6, ln = r & 63;
        int n  = ct * 32 + (ln & 31);
        int k0 = ks * 16 + (ln >> 5) * 8;
        bf16x8 v;
        #pragma unroll
        for (int e = 0; e < 8; ++e)
            v[e] = (__bf16)Wm1[(192 + k0 + e) * 128 + n];
        *reinterpret_cast<bf16x8*>(&wbt[q * 8]) = v;
    }
}

// u/v fp32 LDS, 16B-chunk XOR swizzle: elem index for (row, k)
__device__ __forceinline__ int uvswz(int row, int k) {
    return row * 128 + (((k >> 2) ^ (row & 15)) << 2) + (k & 3);
}

// LDS layout (37632 B -> 4 blocks/CU):
//   @0     uL f32 [21][128] 10752 | overlays: hL bf16 [21][128] (steps1-2), a1L f32 (phase3+)
//   @10752 vL f32 [21][128] 10752 | overlay: spl[21*4] f32 + cat[21] int (steps0-2)
//   @21504 fL bf16 [21][256] swizzled 10752
//   @32256 xL bf16 [21][128] 5376
#define SMEM_SZ 37632

template<int USE_WS>
__global__ __launch_bounds__(256, 4)
void actor_kernel(const float* __restrict__ state, const float* __restrict__ ts,
                  const float* __restrict__ Ws1, const float* __restrict__ bs1,
                  const float* __restrict__ Ws2, const float* __restrict__ bs2,
                  const float* __restrict__ Wm1, const float* __restrict__ bm1,
                  const float* __restrict__ Wm2, const float* __restrict__ bm2,
                  const float* __restrict__ Wa1, const float* __restrict__ ba1,
                  const float* __restrict__ Wa2, const float* __restrict__ ba2,
                  const float* __restrict__ fe3, const __bf16* __restrict__ w2t,
                  const __bf16* __restrict__ wdt, const __bf16* __restrict__ wbt,
                  float* __restrict__ out) {
    __shared__ __align__(16) unsigned char smem[SMEM_SZ];
    float*  uL  = (float*)(smem);
    __bf16* hL  = (__bf16*)(smem);
    float*  a1L = (float*)(smem);
    float*  vL  = (float*)(smem + 10752);
    float*  spl = (float*)(smem + 10752);
    int*    catl= (int*)(smem + 10752 + 336);
    __bf16* fL  = (__bf16*)(smem + 21504);
    __bf16* xL  = (__bf16*)(smem + 32256);

    const int b   = blockIdx.x;
    const int tid = threadIdx.x;
    const int c   = tid & 127;
    const int half= tid >> 7;
    const int i0  = half ? 11 : 0;
    const int NI  = half ? (NOBJ - 11) : 11;
    const int lane = tid & 63;
    const int wave = tid >> 6;
    const int rowA = lane & 31;
    const int hi   = lane >> 5;

    // ---- step 0 ----
    if (tid < NOBJ * 4) {
        int i = tid >> 2, m = tid & 3;
        float v;
        if (m < 2) v = state[b * 63 + i * 3 + m];
        else       v = ftanh(ts[(b * NOBJ + i) * 2 + (m - 2)]);
        spl[tid] = v;
    }
    if (tid >= 128 && tid < 128 + NOBJ) {
        int i = tid - 128;
        catl[i] = (int)state[b * 63 + i * 3 + 2];
    }
    __syncthreads();

    // ---- step 1: h = tanh(sp @ Ws1 + bs1) -> bf16 ----
    {
        float b1 = bs1[c];
        float w0 = Ws1[0 * 128 + c], w1 = Ws1[1 * 128 + c];
        float w2 = Ws1[2 * 128 + c], w3 = Ws1[3 * 128 + c];
        for (int g = 0; g < NI; ++g) {
            int i = i0 + g;
            float acc = b1 + spl[i*4+0]*w0 + spl[i*4+1]*w1 + spl[i*4+2]*w2 + spl[i*4+3]*w3;
            hL[i * 128 + c] = (__bf16)ftanh(acc);
        }
    }
    __syncthreads();

    // ---- step 2: f[:, :128] = tanh(h @ Ws2 + bs2) -> swizzled bf16 fL ----
    {
        float acc[11];
        #pragma unroll
        for (int g = 0; g < 11; ++g) acc[g] = 0.f;
        const unsigned int* hrow = (const unsigned int*)hL;
        for (int k2 = 0; k2 < 64; ++k2) {
            float w0 = Ws2[(2 * k2) * 128 + c];
            float w1 = Ws2[(2 * k2 + 1) * 128 + c];
            #pragma unroll
            for (int g = 0; g < 11; ++g) {
                if (g < NI) {
                    unsigned int pr = hrow[(i0 + g) * 64 + k2];
                    float lo = __uint_as_float(pr << 16);
                    float hh = __uint_as_float(pr & 0xffff0000u);
                    acc[g] = __builtin_fmaf(hh, w1, __builtin_fmaf(lo, w0, acc[g]));
                }
            }
        }
        float b2 = bs2[c];
        for (int g = 0; g < NI; ++g) {
            int i = i0 + g;
            fL[i * 256 + (((c >> 3) ^ (i & 15)) << 3) + (c & 7)] = (__bf16)ftanh(acc[g] + b2);
        }
    }
    for (int idx = tid; idx < NOBJ * 64; idx += 256) {
        int i = idx >> 6, e = idx & 63;
        fL[i * 256 + ((((16 + (e >> 3)) ^ (i & 15))) << 3) + (e & 7)] = (__bf16)fe3[catl[i] * 64 + e];
    }
    __syncthreads();

    // ---- step 3: u = f@Wd + bm1 ; v = f@Wb ----
    if constexpr (USE_WS) {
        // MFMA: M=32 (21 valid rows), wave owns ct = wave (32 cols), K=192
        const int cN = wave * 32 + rowA;
        const int jA = rowA;                      // A row = lane&31
        const int jcA = jA < NOBJ ? jA : NOBJ - 1;
        f32x16 accU, accV;
        #pragma unroll
        for (int r = 0; r < 16; ++r) { accU[r] = 0.f; accV[r] = 0.f; }
        #pragma unroll
        for (int ks = 0; ks < 12; ++ks) {
            int ch = 2 * ks + hi;                 // bf16 16B-chunk index (k0>>3)
            bf16x8 a = *(const bf16x8*)&fL[jcA * 256 + ((ch ^ (jcA & 15)) << 3)];
            int fi = (wave * 12 + ks) * 64 + lane;
            bf16x8 bu = *(const bf16x8*)&wdt[fi * 8];
            bf16x8 bv = *(const bf16x8*)&wbt[fi * 8];
            accU = __builtin_amdgcn_mfma_f32_32x32x16_bf16(a, bu, accU, 0, 0, 0);
            accV = __builtin_amdgcn_mfma_f32_32x32x16_bf16(a, bv, accV, 0, 0, 0);
        }
        float b1 = bm1[cN];
        #pragma unroll
        for (int r = 0; r < 16; ++r) {
            int j = (r & 3) + 8 * (r >> 2) + 4 * hi;
            if (j < NOBJ) {
                uL[uvswz(j, cN)] = accU[r] + b1;
                vL[uvswz(j, cN)] = accV[r];
            }
        }
    } else {
        // VALU fallback (fL is swizzled [21][256])
        float ua[11], va[11];
        #pragma unroll
        for (int g = 0; g < 11; ++g) { ua[g] = 0.f; va[g] = 0.f; }
        const unsigned int* frow = (const unsigned int*)fL;   // row stride 128 dwords
        for (int k2 = 0; k2 < 96; ++k2) {
            int k = 2 * k2;
            float wt0 = Wm1[k * 128 + c],         wt1 = Wm1[(k + 1) * 128 + c];
            float wb0 = Wm1[(192 + k) * 128 + c], wb1 = Wm1[(193 + k) * 128 + c];
            float wd0 = wt0 - wb0, wd1 = wt1 - wb1;
            #pragma unroll
            for (int g = 0; g < 11; ++g) {
                if (g < NI) {
                    int i = i0 + g;
                    int dw = (((k2 >> 2) ^ (i & 15)) << 2) + (k2 & 3);
                    unsigned int pr = frow[i * 128 + dw];
                    float lo = __uint_as_float(pr << 16);
                    float hh = __uint_as_float(pr & 0xffff0000u);
                    ua[g] = __builtin_fmaf(hh, wd1, __builtin_fmaf(lo, wd0, ua[g]));
                    va[g] = __builtin_fmaf(hh, wb1, __builtin_fmaf(lo, wb0, va[g]));
                }
            }
        }
        float b1 = bm1[c];
        for (int g = 0; g < NI; ++g) {
            uL[uvswz(i0 + g, c)] = ua[g] + b1;
            vL[uvswz(i0 + g, c)] = va[g];
        }
    }
    __syncthreads();

    // ---- phase 2: wave-owned i; x[i,:] = tanh(max_j tanh(u_i+v_j)@Wm2 + bm2) ----
    float bm2v[4];
    #pragma unroll
    for (int ct = 0; ct < 4; ++ct) bm2v[ct] = bm2[ct * 32 + rowA];
    const int jcP = rowA < NOBJ ? rowA : NOBJ - 1;

    for (int i = wave; i < NOBJ; i += 4) {
        bf16x8 afr[8];
        #pragma unroll
        for (int ks = 0; ks < 8; ++ks) {
            int c0 = ks * 4 + hi * 2;             // f32 4-elem chunk (k0>>2)
            f32x4 v0 = *(const f32x4*)&vL[jcP * 128 + (((c0)     ^ (jcP & 15)) << 2)];
            f32x4 v1 = *(const f32x4*)&vL[jcP * 128 + (((c0 + 1) ^ (jcP & 15)) << 2)];
            f32x4 u0 = *(const f32x4*)&uL[i * 128 + (((c0)     ^ (i & 15)) << 2)];
            f32x4 u1 = *(const f32x4*)&uL[i * 128 + (((c0 + 1) ^ (i & 15)) << 2)];
            bf16x8 a;
            #pragma unroll
            for (int e = 0; e < 4; ++e) {
                a[e]     = (__bf16)ftanh(u0[e] + v0[e]);
                a[4 + e] = (__bf16)ftanh(u1[e] + v1[e]);
            }
            afr[ks] = a;
        }
        #pragma unroll
        for (int ct = 0; ct < 4; ++ct) {
            int cN = ct * 32 + rowA;
            f32x16 acc;
            #pragma unroll
            for (int r = 0; r < 16; ++r) acc[r] = 0.f;
            #pragma unroll
            for (int ks = 0; ks < 8; ++ks) {
                bf16x8 bb;
                if (USE_WS) {
                    int fi = (ct * 8 + ks) * 64 + lane;
                    bb = *(const bf16x8*)&w2t[fi * 8];
                } else {
                    int k0 = ks * 16 + hi * 8;
                    #pragma unroll
                    for (int e = 0; e < 8; ++e) bb[e] = (__bf16)Wm2[(k0 + e) * 128 + cN];
                }
                acc = __builtin_amdgcn_mfma_f32_32x32x16_bf16(afr[ks], bb, acc, 0, 0, 0);
            }
            float m = -INFINITY;
            #pragma unroll
            for (int r = 0; r < 16; ++r) {
                int j = (r & 3) + 8 * (r >> 2) + 4 * hi;
                if (j < NOBJ && j != i) m = fmaxf(m, acc[r]);
            }
            m = fmaxf(m, __shfl_xor(m, 32));
            if (hi == 0) xL[i * 128 + cN] = (__bf16)ftanh(m + bm2v[ct]);
        }
    }
    __syncthreads();

    // ---- phase 3: a1 = tanh(x @ Wa1 + ba1) (a1 overlays uL) ----
    {
        float acc[11];
        #pragma unroll
        for (int g = 0; g < 11; ++g) acc[g] = 0.f;
        const unsigned int* xrow = (const unsigned int*)xL;
        for (int k2 = 0; k2 < 64; ++k2) {
            float w0 = Wa1[(2 * k2) * 128 + c];
            float w1 = Wa1[(2 * k2 + 1) * 128 + c];
            #pragma unroll
            for (int g = 0; g < 11; ++g) {
                if (g < NI) {
                    unsigned int pr = xrow[(i0 + g) * 64 + k2];
                    float lo = __uint_as_float(pr << 16);
                    float hh = __uint_as_float(pr & 0xffff0000u);
                    acc[g] = __builtin_fmaf(hh, w1, __builtin_fmaf(lo, w0, acc[g]));
                }
            }
        }
        float b1 = ba1[c];
        for (int g = 0; g < NI; ++g)
            a1L[(i0 + g) * 128 + c] = ftanh(acc[g] + b1);
    }
    __syncthreads();

    // ---- head ----
    if (tid < NOBJ * 4) {
        int i = tid >> 2, o = tid & 3;
        float acc = ba2[o];
        for (int kk = 0; kk < 128; ++kk) {
            int k = (kk + i * 5) & 127;
            acc += a1L[i * 128 + k] * Wa2[k * 4 + o];
        }
        if (o < 2) {
            out[b * 42 + i * 2 + o] = 0.3f * ftanh(acc);
        } else {
            float t   = ftanh(acc);
            float lsv = -5.0f + 3.5f * (t + 1.0f);
            out[43008 + b * 42 + i * 2 + (o - 2)] = __expf(lsv);
        }
    }
}

extern "C" void kernel_launch(void* const* d_in, const int* in_sizes, int n_in,
                              void* d_out, int out_size, void* d_ws, size_t ws_size,
                              hipStream_t stream) {
    (void)in_sizes; (void)n_in; (void)out_size;
    const float* state = (const float*)d_in[0];
    const float* ts    = (const float*)d_in[1];
    const float* emb   = (const float*)d_in[2];
    const float* We    = (const float*)d_in[3];
    const float* be    = (const float*)d_in[4];
    const float* Ws1   = (const float*)d_in[5];
    const float* bs1   = (const float*)d_in[6];
    const float* Ws2   = (const float*)d_in[7];
    const float* bs2   = (const float*)d_in[8];
    const float* Wm1   = (const float*)d_in[9];
    const float* bm1   = (const float*)d_in[10];
    const float* Wm2   = (const float*)d_in[11];
    const float* bm2   = (const float*)d_in[12];
    const float* Wa1   = (const float*)d_in[13];
    const float* ba1   = (const float*)d_in[14];
    const float* Wa2   = (const float*)d_in[15];
    const float* ba2   = (const float*)d_in[16];
    float* outp = (float*)d_out;

    float*  fe3 = (float*)d_ws;
    __bf16* w2t = (__bf16*)((char*)d_ws + 1024);
    __bf16* wdt = (__bf16*)((char*)d_ws + 1024 + 32768);
    __bf16* wbt = (__bf16*)((char*)d_ws + 1024 + 32768 + 49152);
    const int use_ws = (ws_size >= (size_t)(1024 + 32768 + 2 * 49152)) ? 1 : 0;

    setup_kernel<<<dim3(33), dim3(256), 0, stream>>>(emb, We, be, Wm2, Wm1,
                                                     fe3, w2t, wdt, wbt, use_ws);
    if (use_ws)
        actor_kernel<1><<<dim3(1024), dim3(256), 0, stream>>>(
            state, ts, Ws1, bs1, Ws2, bs2, Wm1, bm1, Wm2, bm2,
            Wa1, ba1, Wa2, ba2, fe3, w2t, wdt, wbt, outp);
    else
        actor_kernel<0><<<dim3(1024), dim3(256), 0, stream>>>(
            state, ts, Ws1, bs1, Ws2, bs2, Wm1, bm1, Wm2, bm2,
            Wa1, ba1, Wa2, ba2, fe3, w2t, wdt, wbt, outp);
}